// Round 5
// baseline (191.917 us; speedup 1.0000x reference)
//
#include <hip/hip_runtime.h>
#include <hip/hip_bf16.h>
#include <math.h>

// SpectralLinear: out = x @ (M_U * diag(sigma) * M_V) + bias
// Compact WY without explicit T:  T^{-1} = strict_upper(G) + diag(1/beta)
//   A = Umat*T_U (forward subst)   R = T_V*Vmat^T (backward subst)
//   C = (Umat^T S) Vmat ;  E = SV - A*C
//   W = S - [A | E] . [SU^T ; R]
// Inputs U,V are already upper-triangular (setup applies jnp.triu):
//   Umat[r,i] = U[i,r], Vmat[r,i] = V[63-i,r].
// Whole W build fused into ONE kernel (256 blocks = 1/CU, co-resident) with
// grid-wide spin barriers on device-scope flags. ws is re-poisoned to
// 0xAAAAAAAA (negative int) before every launch, so `flag < tag` spins are
// stale-proof without any init pass.
// out = x @ W + bias via bf16 MFMA (Wt = W^T bf16; fp32 accumulate).

#define INSIZE 512
#define NREF 64
#define BATCH 8192

// workspace layout (float slots)
static constexpr int OFF_WT    = 0;                    // 512*512 bf16 = 131072 slots
static constexpr int OFF_SIGMA = 131072;               // 512
static constexpr int OFF_BETAU = OFF_SIGMA + 512;      // 64
static constexpr int OFF_BETAV = OFF_BETAU + 64;       // 64
static constexpr int OFF_GU    = OFF_BETAV + 64;       // 64*64
static constexpr int OFF_GV    = OFF_GU + 4096;        // 64*64
static constexpr int OFF_C     = OFF_GV + 4096;        // 64*64
static constexpr int OFF_PT    = OFF_C + 4096;         // 64*512 (At)
static constexpr int OFF_R     = OFF_PT + 128 * 512;   // 64*512
static constexpr int OFF_FLAGS = OFF_R + 64 * 512;     // 256 ints

__device__ inline float sigma_of(float pv) {
    float s = 1.0f / (1.0f + expf(-pv));
    return 0.55f + 0.9f * (s - 0.5f);   // SIGMA_MIN=0.1, SIGMA_MAX=1.0
}

// grid barrier: block sets its flag to `tag`; thread t spins on flags[t].
// Poison value 0xAAAAAAAA is negative, so `< tag` never passes stale.
__device__ __forceinline__ void gridbar(int* flags, int tag) {
    __syncthreads();
    if (threadIdx.x == 0)
        __hip_atomic_store(flags + blockIdx.x, tag, __ATOMIC_RELEASE,
                           __HIP_MEMORY_SCOPE_AGENT);
    while (__hip_atomic_load(flags + threadIdx.x, __ATOMIC_ACQUIRE,
                             __HIP_MEMORY_SCOPE_AGENT) < tag)
        __builtin_amdgcn_s_sleep(2);
    __syncthreads();
}

// ---------------------------------------------------------------------------
// Fused W build. Grid MUST be 256 blocks x 256 threads (1 block/CU).
__global__ __launch_bounds__(256) void k_build(const float* __restrict__ U,
                                               const float* __restrict__ V,
                                               const float* __restrict__ p,
                                               float* __restrict__ ws) {
    __shared__ float smem[12800];    // phase A: rowi[512]; B: Gs[4096]+bs[64];
                                     // C: Ps[4352]+Qs[4352]+Cs[4096]
    int* flags = (int*)(ws + OFF_FLAGS);
    int b = blockIdx.x, t = threadIdx.x;
    int w = t >> 6, l = t & 63;

    // ---------------- phase A: G_U, G_V, C, sigma ----------------
    if (b < 128) {
        bool isV = (b >= 64);
        int i = isV ? (b - 64) : b;
        const float* src = isV ? V : U;
        int srow = isV ? (63 - i) : i;
        float* rowi = smem;
        for (int c = t; c < INSIZE; c += 256) rowi[c] = src[srow * INSIZE + c];
        __syncthreads();
        float* G = ws + (isV ? OFF_GV : OFF_GU);
        float* beta = ws + (isV ? OFF_BETAV : OFF_BETAU);
        for (int jj = 0; jj < 16; ++jj) {
            int j = w * 16 + jj;
            int jrow = isV ? (63 - j) : j;
            const float* rj = src + jrow * INSIZE;
            float s = 0.f;
            for (int c = l; c < INSIZE; c += 64) s += rowi[c] * rj[c];
            for (int o = 32; o > 0; o >>= 1) s += __shfl_down(s, o, 64);
            if (l == 0) {
                G[i * 64 + j] = s;
                if (j == i) beta[i] = 2.0f / s;
            }
        }
    } else if (b < 192) {
        int i = b - 128;
        float* rowi = smem;
        for (int c = t; c < INSIZE; c += 256)
            rowi[c] = U[i * INSIZE + c] * sigma_of(p[c]);
        __syncthreads();
        float* C = ws + OFF_C;
        for (int jj = 0; jj < 16; ++jj) {
            int j = w * 16 + jj;
            const float* rj = V + (63 - j) * INSIZE;
            float s = 0.f;
            for (int c = l; c < INSIZE; c += 64) s += rowi[c] * rj[c];
            for (int o = 32; o > 0; o >>= 1) s += __shfl_down(s, o, 64);
            if (l == 0) C[i * 64 + j] = s;
        }
    } else if (b == 192) {
        for (int c = t; c < INSIZE; c += 256)
            (ws + OFF_SIGMA)[c] = sigma_of(p[c]);
    }

    gridbar(flags, 1);

    // ---------------- phase B: substitutions (blocks 0..3) ----------------
    if (b < 4) {
        int z = b >> 1;              // 0 = A (forward), 1 = R (backward)
        int r = (b & 1) * 256 + t;   // owned row/col index 0..511
        const float* G = ws + (z ? OFF_GV : OFF_GU);
        const float* beta = ws + (z ? OFF_BETAV : OFF_BETAU);
        float* Gs = smem;
        float* bs = smem + 4096;
        for (int i = t; i < 4096; i += 256) Gs[i] = G[i];
        if (t < 64) bs[t] = beta[t];
        __syncthreads();
        float acc[64];
        if (z == 0) {
            float* At = ws + OFF_PT;
#pragma unroll
            for (int j = 0; j < 64; ++j) {
                float s = U[j * INSIZE + r];          // Umat[r,j], coalesced
#pragma unroll
                for (int m = 0; m < j; ++m) s -= acc[m] * Gs[m * 64 + j];
                acc[j] = s * bs[j];
            }
#pragma unroll
            for (int j = 0; j < 64; ++j) At[j * INSIZE + r] = acc[j];
        } else {
            float* R = ws + OFF_R;
#pragma unroll
            for (int i = 63; i >= 0; --i) {
                float s = V[(63 - i) * INSIZE + r];   // Vmat[r,i], coalesced
#pragma unroll
                for (int m = i + 1; m < 64; ++m) s -= Gs[i * 64 + m] * acc[m];
                acc[i] = s * bs[i];
            }
#pragma unroll
            for (int i = 0; i < 64; ++i) R[i * INSIZE + r] = acc[i];
        }
    }

    gridbar(flags, 2);

    // ---------------- phase C: E + W tile + transpose + bf16 ----------------
    {
        float* Ps = smem;            // [128][34]
        float* Qs = smem + 4352;     // [128][34]
        float* Cs = smem + 8704;     // [4096]
        int r0 = (b >> 4) * 32;
        int c0 = (b & 15) * 32;
        const float* At = ws + OFF_PT;
        const float* R = ws + OFF_R;
        const float* sig = ws + OFF_SIGMA;
        int lr = t & 31, kb = t >> 5;         // kb 0..7
        float sc = sig[c0 + lr];
#pragma unroll
        for (int ii = 0; ii < 8; ++ii) {
            int k = kb + ii * 8;              // 0..63
            Ps[k * 34 + lr] = At[k * INSIZE + r0 + lr];
        }
#pragma unroll
        for (int ii = 0; ii < 16; ++ii) {
            int k = kb + ii * 8;
            Qs[k * 34 + lr] = (k < 64) ? U[k * INSIZE + c0 + lr] * sc
                                       : R[(k - 64) * INSIZE + c0 + lr];
        }
#pragma unroll
        for (int i = 0; i < 16; ++i) Cs[t + i * 256] = (ws + OFF_C)[t + i * 256];
        __syncthreads();
        // Et[j,r] = sig_r V[63-j,r] - sum_i At[i,r] C[i,j]  -> Ps rows 64..127
        float sr = sig[r0 + lr];
#pragma unroll
        for (int ii = 0; ii < 8; ++ii) {
            int j = kb * 8 + ii;              // 0..63
            float e = sr * V[(63 - j) * INSIZE + r0 + lr];
#pragma unroll 8
            for (int i = 0; i < 64; ++i)
                e -= Ps[i * 34 + lr] * Cs[i * 64 + j];
            Ps[(64 + j) * 34 + lr] = e;
        }
        __syncthreads();
        // 32x32x128 tile GEMM, 2x2 per thread
        int ty = t >> 4, tx = t & 15;
        float a00 = 0.f, a01 = 0.f, a10 = 0.f, a11 = 0.f;
#pragma unroll
        for (int k = 0; k < 128; ++k) {
            float2 a = *(const float2*)&Ps[k * 34 + ty * 2];
            float2 bq = *(const float2*)&Qs[k * 34 + tx * 2];
            a00 += a.x * bq.x; a01 += a.x * bq.y;
            a10 += a.y * bq.x; a11 += a.y * bq.y;
        }
        int rg = r0 + ty * 2, cg = c0 + tx * 2;
        float w00 = ((rg == cg) ? sig[rg] : 0.f) - a00;
        float w01 = ((rg == cg + 1) ? sig[rg] : 0.f) - a01;
        float w10 = ((rg + 1 == cg) ? sig[rg + 1] : 0.f) - a10;
        float w11 = ((rg + 1 == cg + 1) ? sig[rg + 1] : 0.f) - a11;
        unsigned short* Wt = (unsigned short*)(ws + OFF_WT);
        __hip_bfloat162 lo = __float22bfloat162_rn(make_float2(w00, w10));
        __hip_bfloat162 hi = __float22bfloat162_rn(make_float2(w01, w11));
        *(__hip_bfloat162*)&Wt[cg * INSIZE + rg] = lo;
        *(__hip_bfloat162*)&Wt[(cg + 1) * INSIZE + rg] = hi;
    }
}

// ---------------------------------------------------------------------------
// out = x @ W + bias : bf16 MFMA, 64x128 block tile, BK=32, 512 blocks (2/CU).
// Validated in R2-R4; unchanged.
//   A: m=lane&15, k=(lane>>4)*8+j ; B: n=lane&15, k=(lane>>4)*8+j
//   C/D: col=lane&15, row=(lane>>4)*4+reg
typedef __attribute__((ext_vector_type(8))) short short8;
typedef __attribute__((ext_vector_type(4))) float float4v;

__global__ __launch_bounds__(256) void k_gemm(const float* __restrict__ X,
                                              const float* __restrict__ ws,
                                              const float* __restrict__ bias,
                                              float* __restrict__ out) {
    __shared__ float As[64 * 32];               // 8 KB, chunk-swizzled
    __shared__ unsigned short Bs[128 * 32];     // 8 KB, chunk-swizzled
    const unsigned short* Wt = (const unsigned short*)(ws + OFF_WT);

    int L = blockIdx.x;              // 0..511
    int inner = L & 7;
    int bn = (L >> 3) & 3;
    int bm = (L >> 5) * 8 + inner;   // 0..127
    int row0 = bm * 64, col0 = bn * 128;

    int t = threadIdx.x;
    int l = t & 63, w = t >> 6;
    int wm = (w & 1) * 32, wn = (w >> 1) * 64;

    float4v acc[2][4] = {};
    int quad = l >> 4;
    int lan = l & 15;

    for (int k0 = 0; k0 < INSIZE; k0 += 32) {
        __syncthreads();
#pragma unroll
        for (int i = 0; i < 2; ++i) {
            int P = i * 256 + t;
            int prow = P >> 3, pc = P & 7;
            int lc = pc ^ (prow & 7);
            const float* g = X + (size_t)(row0 + prow) * INSIZE + k0 + lc * 4;
            __builtin_amdgcn_global_load_lds(
                (const __attribute__((address_space(1))) void*)g,
                (__attribute__((address_space(3))) void*)(As + P * 4), 16, 0, 0);
        }
#pragma unroll
        for (int i = 0; i < 2; ++i) {
            int P = i * 256 + t;
            int prow = P >> 2, pc = P & 3;
            int lc = pc ^ ((prow >> 1) & 3);
            const unsigned short* g = Wt + (size_t)(col0 + prow) * INSIZE + k0 + lc * 8;
            __builtin_amdgcn_global_load_lds(
                (const __attribute__((address_space(1))) void*)g,
                (__attribute__((address_space(3))) void*)(Bs + P * 8), 16, 0, 0);
        }
        __syncthreads();

        short8 af[2];
        short8 bf[4];
#pragma unroll
        for (int mi = 0; mi < 2; ++mi) {
            int rl = wm + mi * 16 + lan;
            int c0q = quad * 2;
            const float4v lo = *(const float4v*)(As + (rl * 8 + (c0q ^ (rl & 7))) * 4);
            const float4v hi = *(const float4v*)(As + (rl * 8 + ((c0q + 1) ^ (rl & 7))) * 4);
            union { short8 s; __hip_bfloat162 h[4]; } u;
            u.h[0] = __float22bfloat162_rn(make_float2(lo[0], lo[1]));
            u.h[1] = __float22bfloat162_rn(make_float2(lo[2], lo[3]));
            u.h[2] = __float22bfloat162_rn(make_float2(hi[0], hi[1]));
            u.h[3] = __float22bfloat162_rn(make_float2(hi[2], hi[3]));
            af[mi] = u.s;
        }
#pragma unroll
        for (int ni = 0; ni < 4; ++ni) {
            int rn = wn + ni * 16 + lan;
            int c = quad ^ ((rn >> 1) & 3);
            bf[ni] = *(const short8*)(Bs + (rn * 4 + c) * 8);
        }
#pragma unroll
        for (int mi = 0; mi < 2; ++mi)
#pragma unroll
            for (int ni = 0; ni < 4; ++ni)
                acc[mi][ni] = __builtin_amdgcn_mfma_f32_16x16x32_bf16(
                    af[mi], bf[ni], acc[mi][ni], 0, 0, 0);
    }

#pragma unroll
    for (int ni = 0; ni < 4; ++ni) {
        int c = col0 + wn + ni * 16 + lan;
        float bv = bias[c];
#pragma unroll
        for (int mi = 0; mi < 2; ++mi) {
            int rbase = row0 + wm + mi * 16 + quad * 4;
#pragma unroll
            for (int r = 0; r < 4; ++r)
                out[(size_t)(rbase + r) * INSIZE + c] = acc[mi][ni][r] + bv;
        }
    }
}

// ---------------------------------------------------------------------------
extern "C" void kernel_launch(void* const* d_in, const int* in_sizes, int n_in,
                              void* d_out, int out_size, void* d_ws, size_t ws_size,
                              hipStream_t stream) {
    const float* x    = (const float*)d_in[0];
    const float* p    = (const float*)d_in[1];
    const float* U    = (const float*)d_in[2];
    const float* V    = (const float*)d_in[3];
    const float* bias = (const float*)d_in[4];
    float* ws  = (float*)d_ws;
    float* out = (float*)d_out;

    k_build<<<256, 256, 0, stream>>>(U, V, p, ws);
    k_gemm<<<512, 256, 0, stream>>>(x, ws, bias, out);
}

// Round 6
// 125.458 us; speedup vs baseline: 1.5297x; 1.5297x over previous
//
#include <hip/hip_runtime.h>
#include <hip/hip_bf16.h>
#include <math.h>

// SpectralLinear: out = x @ (M_U * diag(sigma) * M_V) + bias
// Compact WY without explicit T:  T^{-1} = strict_upper(G) + diag(1/beta)
//   A = Umat*T_U (forward subst)   R = T_V*Vmat^T (backward subst)
//   C = (Umat^T S) Vmat ;  E = SV - A*C
//   W = S - [A | E] . [SU^T ; R]
// Inputs U,V are already upper-triangular (setup applies jnp.triu):
//   Umat[r,i] = U[i,r], Vmat[r,i] = V[63-i,r].
// out = x @ W + bias via bf16 MFMA (Wt = W^T bf16; fp32 accumulate).
// NOTE (R5 lesson): single-kernel fusion with device-scope spin barriers cost
// ~120 us in coherence-point polling -- separate kernels are faster here.

#define INSIZE 512
#define NREF 64
#define BATCH 8192

// workspace layout (float slots)
static constexpr int OFF_WT    = 0;                    // 512*512 bf16 = 131072 slots
static constexpr int OFF_SIGMA = 131072;               // 512
static constexpr int OFF_BETAU = OFF_SIGMA + 512;      // 64
static constexpr int OFF_BETAV = OFF_BETAU + 64;       // 64
static constexpr int OFF_GU    = OFF_BETAV + 64;       // 64*64
static constexpr int OFF_GV    = OFF_GU + 4096;        // 64*64
static constexpr int OFF_C     = OFF_GV + 4096;        // 64*64
static constexpr int OFF_PT    = OFF_C + 4096;         // 64*512 (At)
static constexpr int OFF_R     = OFF_PT + 128 * 512;   // 64*512

__device__ inline float sigma_of(float pv) {
    float s = 1.0f / (1.0f + expf(-pv));
    return 0.55f + 0.9f * (s - 0.5f);   // SIGMA_MIN=0.1, SIGMA_MAX=1.0
}

// ---------------------------------------------------------------------------
// k_prep: blocks 0..63   -> G_U row i (+beta_U[i])
//         blocks 64..127 -> G_V row i (+beta_V[i])  (packed order: row 63-i)
//         blocks 128..191-> C row i:  C[i,j] = sum_c U[i,c] sig_c V[63-j,c]
//         block 192      -> sigma array
__global__ __launch_bounds__(256) void k_prep(const float* __restrict__ U,
                                              const float* __restrict__ V,
                                              const float* __restrict__ p,
                                              float* __restrict__ ws) {
    int b = blockIdx.x, t = threadIdx.x;
    if (b == 192) {
        for (int c = t; c < INSIZE; c += 256)
            (ws + OFF_SIGMA)[c] = sigma_of(p[c]);
        return;
    }
    __shared__ float rowi[INSIZE];
    int w = t >> 6, l = t & 63;
    if (b < 128) {
        bool isV = (b >= 64);
        int i = isV ? (b - 64) : b;
        const float* src = isV ? V : U;
        int srow = isV ? (63 - i) : i;
        for (int c = t; c < INSIZE; c += 256) rowi[c] = src[srow * INSIZE + c];
        __syncthreads();
        float* G = ws + (isV ? OFF_GV : OFF_GU);
        float* beta = ws + (isV ? OFF_BETAV : OFF_BETAU);
        for (int jj = 0; jj < 16; ++jj) {
            int j = w * 16 + jj;
            int jrow = isV ? (63 - j) : j;
            const float* rj = src + jrow * INSIZE;
            float s = 0.f;
            for (int c = l; c < INSIZE; c += 64) s += rowi[c] * rj[c];
            for (int o = 32; o > 0; o >>= 1) s += __shfl_down(s, o, 64);
            if (l == 0) {
                G[i * 64 + j] = s;
                if (j == i) beta[i] = 2.0f / s;
            }
        }
    } else {
        int i = b - 128;
        for (int c = t; c < INSIZE; c += 256)
            rowi[c] = U[i * INSIZE + c] * sigma_of(p[c]);
        __syncthreads();
        float* C = ws + OFF_C;
        for (int jj = 0; jj < 16; ++jj) {
            int j = w * 16 + jj;
            const float* rj = V + (63 - j) * INSIZE;
            float s = 0.f;
            for (int c = l; c < INSIZE; c += 64) s += rowi[c] * rj[c];
            for (int o = 32; o > 0; o >>= 1) s += __shfl_down(s, o, 64);
            if (l == 0) C[i * 64 + j] = s;
        }
    }
}

// ---------------------------------------------------------------------------
// A and R via register-resident substitution, row-contiguous (b128) LDS reads.
// block 0: At[j, t] = A[t, j]  forward, partial-update form:
//    part[j] = Umat[t,j];  for m: a_m = part[m]*b_m;  part[j>m] -= a_m*G[m][j]
// block 1: R[i, t]  backward, gather form (G row i, m>i consecutive).
__global__ __launch_bounds__(512) void k_AR(const float* __restrict__ U,
                                            const float* __restrict__ V,
                                            float* __restrict__ ws) {
    __shared__ float Gs[64 * 64];
    __shared__ float bs[64];
    int z = blockIdx.x;
    int t = threadIdx.x;             // 0..511
    const float* G = ws + (z ? OFF_GV : OFF_GU);
    const float* beta = ws + (z ? OFF_BETAV : OFF_BETAU);
    for (int i = t; i < 1024; i += 512)
        *(float4*)&Gs[i * 4] = *(const float4*)&G[i * 4];
    if (t < 64) bs[t] = beta[t];
    __syncthreads();
    float part[64];
    if (z == 0) {
        float* At = ws + OFF_PT;
#pragma unroll
        for (int j = 0; j < 64; ++j) part[j] = U[j * INSIZE + t];   // coalesced
#pragma unroll
        for (int m = 0; m < 64; ++m) {
            float am = part[m] * bs[m];
            part[m] = am;
#pragma unroll
            for (int j = m + 1; j < 64; ++j)
                part[j] -= am * Gs[m * 64 + j];    // row m, consecutive -> b128
        }
#pragma unroll
        for (int j = 0; j < 64; ++j) At[j * INSIZE + t] = part[j];
    } else {
        float* R = ws + OFF_R;
#pragma unroll
        for (int i = 0; i < 64; ++i) part[i] = V[(63 - i) * INSIZE + t];
#pragma unroll
        for (int i = 63; i >= 0; --i) {
            float s = part[i];
#pragma unroll
            for (int m = i + 1; m < 64; ++m)
                s -= Gs[i * 64 + m] * part[m];     // row i, consecutive -> b128
            part[i] = s * bs[i];
        }
#pragma unroll
        for (int i = 0; i < 64; ++i) R[i * INSIZE + t] = part[i];
    }
}

// ---------------------------------------------------------------------------
// Fused E + W build + transpose + bf16 cast (per 32x32 output tile):
//   Ps rows 0..63  = At tile (loaded)
//   Ps rows 64..127= Et in-LDS: Et[j,r] = sig_r V[63-j,r] - sum_i At[i,r] C[i,j]
//   Q[k,c] = (k<64) ? U[k,c]*sig_c : R[k-64,c]
//   W[r,c] = (r==c)*sig_r - sum_k Ps[k][r]*Qs[k][c];  Wt[c*512+r]=bf16(W[r,c])
__global__ __launch_bounds__(256) void k_WtE(const float* __restrict__ U,
                                             const float* __restrict__ V,
                                             float* __restrict__ ws) {
    __shared__ float Ps[128][34];
    __shared__ float Qs[128][34];
    __shared__ float Cs[4096];
    int t = threadIdx.x;
    int r0 = (blockIdx.x >> 4) * 32;
    int c0 = (blockIdx.x & 15) * 32;
    const float* At = ws + OFF_PT;
    const float* R = ws + OFF_R;
    const float* sig = ws + OFF_SIGMA;
    int lr = t & 31, kb = t >> 5;         // kb 0..7
    float sc = sig[c0 + lr];
#pragma unroll
    for (int ii = 0; ii < 8; ++ii) {
        int k = kb + ii * 8;              // 0..63
        Ps[k][lr] = At[k * INSIZE + r0 + lr];
    }
#pragma unroll
    for (int ii = 0; ii < 16; ++ii) {
        int k = kb + ii * 8;
        Qs[k][lr] = (k < 64) ? U[k * INSIZE + c0 + lr] * sc
                             : R[(k - 64) * INSIZE + c0 + lr];
    }
#pragma unroll
    for (int i = 0; i < 16; ++i) Cs[t + i * 256] = (ws + OFF_C)[t + i * 256];
    __syncthreads();
    float sr = sig[r0 + lr];
#pragma unroll
    for (int ii = 0; ii < 8; ++ii) {
        int j = kb * 8 + ii;              // 0..63
        float e = sr * V[(63 - j) * INSIZE + r0 + lr];
#pragma unroll 8
        for (int i = 0; i < 64; ++i)
            e -= Ps[i][lr] * Cs[i * 64 + j];
        Ps[64 + j][lr] = e;
    }
    __syncthreads();
    int ty = t >> 4, tx = t & 15;
    float a00 = 0.f, a01 = 0.f, a10 = 0.f, a11 = 0.f;
#pragma unroll
    for (int k = 0; k < 128; ++k) {
        float2 a = *(const float2*)&Ps[k][ty * 2];
        float2 bq = *(const float2*)&Qs[k][tx * 2];
        a00 += a.x * bq.x; a01 += a.x * bq.y;
        a10 += a.y * bq.x; a11 += a.y * bq.y;
    }
    int rg = r0 + ty * 2, cg = c0 + tx * 2;
    float w00 = ((rg == cg) ? sig[rg] : 0.f) - a00;
    float w01 = ((rg == cg + 1) ? sig[rg] : 0.f) - a01;
    float w10 = ((rg + 1 == cg) ? sig[rg + 1] : 0.f) - a10;
    float w11 = ((rg + 1 == cg + 1) ? sig[rg + 1] : 0.f) - a11;
    unsigned short* Wt = (unsigned short*)(ws + OFF_WT);
    __hip_bfloat162 lo = __float22bfloat162_rn(make_float2(w00, w10));
    __hip_bfloat162 hi = __float22bfloat162_rn(make_float2(w01, w11));
    *(__hip_bfloat162*)&Wt[cg * INSIZE + rg] = lo;
    *(__hip_bfloat162*)&Wt[(cg + 1) * INSIZE + rg] = hi;
}

// ---------------------------------------------------------------------------
// out = x @ W + bias : bf16 MFMA, 64x128 block tile, BK=32, 512 blocks (2/CU).
// Validated in R2-R4; unchanged.
//   A: m=lane&15, k=(lane>>4)*8+j ; B: n=lane&15, k=(lane>>4)*8+j
//   C/D: col=lane&15, row=(lane>>4)*4+reg
typedef __attribute__((ext_vector_type(8))) short short8;
typedef __attribute__((ext_vector_type(4))) float float4v;

__global__ __launch_bounds__(256) void k_gemm(const float* __restrict__ X,
                                              const float* __restrict__ ws,
                                              const float* __restrict__ bias,
                                              float* __restrict__ out) {
    __shared__ float As[64 * 32];               // 8 KB, chunk-swizzled
    __shared__ unsigned short Bs[128 * 32];     // 8 KB, chunk-swizzled
    const unsigned short* Wt = (const unsigned short*)(ws + OFF_WT);

    int L = blockIdx.x;              // 0..511
    int inner = L & 7;
    int bn = (L >> 3) & 3;
    int bm = (L >> 5) * 8 + inner;   // 0..127
    int row0 = bm * 64, col0 = bn * 128;

    int t = threadIdx.x;
    int l = t & 63, w = t >> 6;
    int wm = (w & 1) * 32, wn = (w >> 1) * 64;

    float4v acc[2][4] = {};
    int quad = l >> 4;
    int lan = l & 15;

    for (int k0 = 0; k0 < INSIZE; k0 += 32) {
        __syncthreads();
#pragma unroll
        for (int i = 0; i < 2; ++i) {
            int P = i * 256 + t;
            int prow = P >> 3, pc = P & 7;
            int lc = pc ^ (prow & 7);
            const float* g = X + (size_t)(row0 + prow) * INSIZE + k0 + lc * 4;
            __builtin_amdgcn_global_load_lds(
                (const __attribute__((address_space(1))) void*)g,
                (__attribute__((address_space(3))) void*)(As + P * 4), 16, 0, 0);
        }
#pragma unroll
        for (int i = 0; i < 2; ++i) {
            int P = i * 256 + t;
            int prow = P >> 2, pc = P & 3;
            int lc = pc ^ ((prow >> 1) & 3);
            const unsigned short* g = Wt + (size_t)(col0 + prow) * INSIZE + k0 + lc * 8;
            __builtin_amdgcn_global_load_lds(
                (const __attribute__((address_space(1))) void*)g,
                (__attribute__((address_space(3))) void*)(Bs + P * 8), 16, 0, 0);
        }
        __syncthreads();

        short8 af[2];
        short8 bf[4];
#pragma unroll
        for (int mi = 0; mi < 2; ++mi) {
            int rl = wm + mi * 16 + lan;
            int c0q = quad * 2;
            const float4v lo = *(const float4v*)(As + (rl * 8 + (c0q ^ (rl & 7))) * 4);
            const float4v hi = *(const float4v*)(As + (rl * 8 + ((c0q + 1) ^ (rl & 7))) * 4);
            union { short8 s; __hip_bfloat162 h[4]; } u;
            u.h[0] = __float22bfloat162_rn(make_float2(lo[0], lo[1]));
            u.h[1] = __float22bfloat162_rn(make_float2(lo[2], lo[3]));
            u.h[2] = __float22bfloat162_rn(make_float2(hi[0], hi[1]));
            u.h[3] = __float22bfloat162_rn(make_float2(hi[2], hi[3]));
            af[mi] = u.s;
        }
#pragma unroll
        for (int ni = 0; ni < 4; ++ni) {
            int rn = wn + ni * 16 + lan;
            int c = quad ^ ((rn >> 1) & 3);
            bf[ni] = *(const short8*)(Bs + (rn * 4 + c) * 8);
        }
#pragma unroll
        for (int mi = 0; mi < 2; ++mi)
#pragma unroll
            for (int ni = 0; ni < 4; ++ni)
                acc[mi][ni] = __builtin_amdgcn_mfma_f32_16x16x32_bf16(
                    af[mi], bf[ni], acc[mi][ni], 0, 0, 0);
    }

#pragma unroll
    for (int ni = 0; ni < 4; ++ni) {
        int c = col0 + wn + ni * 16 + lan;
        float bv = bias[c];
#pragma unroll
        for (int mi = 0; mi < 2; ++mi) {
            int rbase = row0 + wm + mi * 16 + quad * 4;
#pragma unroll
            for (int r = 0; r < 4; ++r)
                out[(size_t)(rbase + r) * INSIZE + c] = acc[mi][ni][r] + bv;
        }
    }
}

// ---------------------------------------------------------------------------
extern "C" void kernel_launch(void* const* d_in, const int* in_sizes, int n_in,
                              void* d_out, int out_size, void* d_ws, size_t ws_size,
                              hipStream_t stream) {
    const float* x    = (const float*)d_in[0];
    const float* p    = (const float*)d_in[1];
    const float* U    = (const float*)d_in[2];
    const float* V    = (const float*)d_in[3];
    const float* bias = (const float*)d_in[4];
    float* ws  = (float*)d_ws;
    float* out = (float*)d_out;

    k_prep<<<193, 256, 0, stream>>>(U, V, p, ws);
    k_AR<<<2, 512, 0, stream>>>(U, V, ws);
    k_WtE<<<256, 256, 0, stream>>>(U, V, ws);
    k_gemm<<<512, 256, 0, stream>>>(x, ws, bias, out);
}